// Round 4
// baseline (356.261 us; speedup 1.0000x reference)
//
#include <hip/hip_runtime.h>
#include <math.h>

#define NUM_BINS 100
#define EPS 1e-6f

// ws layout (uint32): [0..99] pos-bin counts, [100..199] neg-bin counts, [200] pos pixel count
#define WS_WORDS (2 * NUM_BINS + 1)

__global__ void hml_init_ws(unsigned int* __restrict__ ws) {
    int i = blockIdx.x * blockDim.x + threadIdx.x;
    if (i < WS_WORDS) ws[i] = 0u;
}

// C=32 specialized: 2 px/thread (float2) -> 8192 waves (32/CU), channel
// batches of 4 (8x8B loads in flight, ~16 data VGPRs). launch_bounds(256,8)
// caps at 64 VGPR for 8 waves/SIMD; batch kept small so it fits w/o spill
// (R1 spilled with a 32-reg batch under the same cap; R2 showed per-wave
// load depth doesn't matter — chip-wide wave concurrency does).
__global__ __launch_bounds__(256, 8) void hml_hist32(
    const float2* __restrict__ f0, const float2* __restrict__ f1,
    const int2* __restrict__ gt, unsigned int* __restrict__ ws, int hw2)
{
    __shared__ unsigned int sh[WS_WORDS];
    for (int i = threadIdx.x; i < WS_WORDS; i += 256) sh[i] = 0u;
    __syncthreads();

    const int idx = blockIdx.x * 256 + threadIdx.x;

    int2 g = gt[idx];
    float s0 = 0.f, s1 = 0.f;

    #pragma unroll
    for (int cg = 0; cg < 32; cg += 4) {
        float2 a[4], b[4];
        #pragma unroll
        for (int j = 0; j < 4; ++j) a[j] = f0[(size_t)(cg + j) * hw2 + idx];
        #pragma unroll
        for (int j = 0; j < 4; ++j) b[j] = f1[(size_t)(cg + j) * hw2 + idx];
        #pragma unroll
        for (int j = 0; j < 4; ++j) {
            float dx = a[j].x - b[j].x + EPS;
            float dy = a[j].y - b[j].y + EPS;
            s0 = fmaf(dx, dx, s0);
            s1 = fmaf(dy, dy, s1);
        }
    }

    float d0 = sqrtf(s0), d1 = sqrtf(s1);

    // pos-pixel count: shfl-reduce per wave, one LDS atomic per wave
    int posc = (g.x == 0) + (g.y == 0);
    for (int off = 32; off > 0; off >>= 1)
        posc += __shfl_down(posc, off, 64);
    if ((threadIdx.x & 63) == 0 && posc)
        atomicAdd(&sh[2 * NUM_BINS], (unsigned)posc);

    // histc: values in [0,1] only (d>=0 from sqrt); floor(d*100) clip to 99
    if (d0 <= 1.0f) {
        int bin = (int)(d0 * (float)NUM_BINS);
        if (bin > NUM_BINS - 1) bin = NUM_BINS - 1;
        atomicAdd(&sh[bin + ((g.x != 0) ? NUM_BINS : 0)], 1u);
    }
    if (d1 <= 1.0f) {
        int bin = (int)(d1 * (float)NUM_BINS);
        if (bin > NUM_BINS - 1) bin = NUM_BINS - 1;
        atomicAdd(&sh[bin + ((g.y != 0) ? NUM_BINS : 0)], 1u);
    }

    __syncthreads();
    for (int i = threadIdx.x; i < WS_WORDS; i += 256) {
        unsigned v = sh[i];
        if (v) atomicAdd(&ws[i], v);
    }
}

// Generic fallback (any C, hw multiple of 4).
__global__ __launch_bounds__(256) void hml_hist_generic(
    const float* __restrict__ f0, const float* __restrict__ f1,
    const int* __restrict__ gt, unsigned int* __restrict__ ws,
    int hw, int C)
{
    __shared__ unsigned int sh[WS_WORDS];
    for (int i = threadIdx.x; i < WS_WORDS; i += blockDim.x) sh[i] = 0u;
    __syncthreads();

    const int hw4 = hw >> 2;
    const int idx = blockIdx.x * blockDim.x + threadIdx.x;

    if (idx < hw4) {
        const float4* __restrict__ f0v = (const float4*)f0;
        const float4* __restrict__ f1v = (const float4*)f1;
        float s0 = 0.f, s1 = 0.f, s2 = 0.f, s3 = 0.f;
        for (int c = 0; c < C; ++c) {
            float4 a = f0v[(size_t)c * hw4 + idx];
            float4 b = f1v[(size_t)c * hw4 + idx];
            float e0 = a.x - b.x + EPS, e1 = a.y - b.y + EPS;
            float e2 = a.z - b.z + EPS, e3 = a.w - b.w + EPS;
            s0 = fmaf(e0, e0, s0); s1 = fmaf(e1, e1, s1);
            s2 = fmaf(e2, e2, s2); s3 = fmaf(e3, e3, s3);
        }
        int4 g = ((const int4*)gt)[idx];
        float d[4] = { sqrtf(s0), sqrtf(s1), sqrtf(s2), sqrtf(s3) };
        int gg[4] = { g.x, g.y, g.z, g.w };
        int posc = 0;
        #pragma unroll
        for (int k = 0; k < 4; ++k) {
            posc += (gg[k] == 0) ? 1 : 0;
            float dd = d[k];
            if (dd <= 1.0f) {
                int bin = (int)(dd * (float)NUM_BINS);
                if (bin > NUM_BINS - 1) bin = NUM_BINS - 1;
                atomicAdd(&sh[bin + ((gg[k] != 0) ? NUM_BINS : 0)], 1u);
            }
        }
        if (posc) atomicAdd(&sh[2 * NUM_BINS], (unsigned)posc);
    }
    __syncthreads();
    for (int i = threadIdx.x; i < WS_WORDS; i += blockDim.x) {
        unsigned v = sh[i];
        if (v) atomicAdd(&ws[i], v);
    }
}

__global__ void hml_final(const unsigned int* __restrict__ ws,
                          float* __restrict__ out, int hw)
{
    __shared__ float terms[NUM_BINS];
    int i = threadIdx.x;
    unsigned pos = ws[2 * NUM_BINS];
    float pos_size = (float)pos;
    float neg_size = (float)(hw - (int)pos);
    if (i < NUM_BINS) {
        float hp = (float)ws[i] / pos_size;
        unsigned cn = ws[NUM_BINS + i];
        float hn = (float)cn / neg_size;
        terms[i] = (cn > 0u) ? hn * (logf(hn) - hp) : 0.0f;
    }
    __syncthreads();
    if (i == 0) {
        float s = 0.f;
        for (int k = 0; k < NUM_BINS; ++k) s += terms[k];
        out[0] = 1.0f + s / (float)NUM_BINS;
    }
}

extern "C" void kernel_launch(void* const* d_in, const int* in_sizes, int n_in,
                              void* d_out, int out_size, void* d_ws, size_t ws_size,
                              hipStream_t stream) {
    const float* f0 = (const float*)d_in[0];
    const float* f1 = (const float*)d_in[1];
    const int*   gt = (const int*)d_in[2];
    float* out = (float*)d_out;
    unsigned int* ws = (unsigned int*)d_ws;

    const int hw = in_sizes[2];          // h*w (= 1024*1024)
    const int C  = in_sizes[0] / hw;     // channels (= 32)

    hml_init_ws<<<1, 256, 0, stream>>>(ws);

    if (C == 32 && (hw & 511) == 0) {
        const int hw2 = hw >> 1;
        const int blocks = hw2 / 256;    // 2048 at 1024x1024
        hml_hist32<<<blocks, 256, 0, stream>>>(
            (const float2*)f0, (const float2*)f1, (const int2*)gt, ws, hw2);
    } else {
        const int hw4 = hw >> 2;
        const int blocks = (hw4 + 255) / 256;
        hml_hist_generic<<<blocks, 256, 0, stream>>>(f0, f1, gt, ws, hw, C);
    }

    hml_final<<<1, 128, 0, stream>>>(ws, out, hw);
}

// Round 6
// 262.209 us; speedup vs baseline: 1.3587x; 1.3587x over previous
//
#include <hip/hip_runtime.h>
#include <math.h>

#define NUM_BINS 100
#define EPS 1e-6f

// ws layout (uint32): [0..99] pos-bin counts, [100..199] neg-bin counts, [200] pos pixel count
#define WS_WORDS (2 * NUM_BINS + 1)

// native vector types: __builtin_nontemporal_load requires these (not HIP_vector_type)
typedef float  vfloat4 __attribute__((ext_vector_type(4)));
typedef int    vint4   __attribute__((ext_vector_type(4)));

__global__ void hml_init_ws(unsigned int* __restrict__ ws) {
    int i = blockIdx.x * blockDim.x + threadIdx.x;
    if (i < WS_WORDS) ws[i] = 0u;
}

// C=32 specialized: 4 px/thread via float4, channel batches of 4, NO
// launch_bounds cap (R2 config: VGPR=132, zero spill, 106us). Single change
// vs R2: feature loads are non-temporal (streaming, single-use) to try to
// lift the ~2.5 TB/s per-CU delivered-BW cap (L1 MSHR theory).
// Guard metric: WRITE_SIZE must stay ~337 B (no spill).
__global__ __launch_bounds__(256) void hml_hist32(
    const vfloat4* __restrict__ f0v, const vfloat4* __restrict__ f1v,
    const vint4* __restrict__ gt, unsigned int* __restrict__ ws, int hw4)
{
    __shared__ unsigned int sh[WS_WORDS];
    for (int i = threadIdx.x; i < WS_WORDS; i += 256) sh[i] = 0u;
    __syncthreads();

    const int idx = blockIdx.x * 256 + threadIdx.x;

    vint4 g = gt[idx];
    float s0 = 0.f, s1 = 0.f, s2 = 0.f, s3 = 0.f;

    #pragma unroll
    for (int cg = 0; cg < 32; cg += 4) {
        vfloat4 a[4], b[4];
        #pragma unroll
        for (int j = 0; j < 4; ++j)
            a[j] = __builtin_nontemporal_load(&f0v[(size_t)(cg + j) * hw4 + idx]);
        #pragma unroll
        for (int j = 0; j < 4; ++j)
            b[j] = __builtin_nontemporal_load(&f1v[(size_t)(cg + j) * hw4 + idx]);
        #pragma unroll
        for (int j = 0; j < 4; ++j) {
            float e0 = a[j].x - b[j].x + EPS;
            float e1 = a[j].y - b[j].y + EPS;
            float e2 = a[j].z - b[j].z + EPS;
            float e3 = a[j].w - b[j].w + EPS;
            s0 = fmaf(e0, e0, s0);
            s1 = fmaf(e1, e1, s1);
            s2 = fmaf(e2, e2, s2);
            s3 = fmaf(e3, e3, s3);
        }
    }

    float d[4] = { sqrtf(s0), sqrtf(s1), sqrtf(s2), sqrtf(s3) };
    int gg[4] = { g.x, g.y, g.z, g.w };

    // pos-pixel count: shfl-reduce per wave, one LDS atomic per wave
    int posc = (gg[0] == 0) + (gg[1] == 0) + (gg[2] == 0) + (gg[3] == 0);
    for (int off = 32; off > 0; off >>= 1)
        posc += __shfl_down(posc, off, 64);
    if ((threadIdx.x & 63) == 0 && posc)
        atomicAdd(&sh[2 * NUM_BINS], (unsigned)posc);

    #pragma unroll
    for (int k = 0; k < 4; ++k) {
        float dd = d[k];
        // histc: values in [0,1] only (dd>=0 from sqrt); floor(d*100) clip 99
        if (dd <= 1.0f) {
            int bin = (int)(dd * (float)NUM_BINS);
            if (bin > NUM_BINS - 1) bin = NUM_BINS - 1;
            atomicAdd(&sh[bin + ((gg[k] != 0) ? NUM_BINS : 0)], 1u);
        }
    }

    __syncthreads();
    for (int i = threadIdx.x; i < WS_WORDS; i += 256) {
        unsigned v = sh[i];
        if (v) atomicAdd(&ws[i], v);
    }
}

// Generic fallback (any C, hw multiple of 4).
__global__ __launch_bounds__(256) void hml_hist_generic(
    const float* __restrict__ f0, const float* __restrict__ f1,
    const int* __restrict__ gt, unsigned int* __restrict__ ws,
    int hw, int C)
{
    __shared__ unsigned int sh[WS_WORDS];
    for (int i = threadIdx.x; i < WS_WORDS; i += blockDim.x) sh[i] = 0u;
    __syncthreads();

    const int hw4 = hw >> 2;
    const int idx = blockIdx.x * blockDim.x + threadIdx.x;

    if (idx < hw4) {
        const float4* __restrict__ f0v = (const float4*)f0;
        const float4* __restrict__ f1v = (const float4*)f1;
        float s0 = 0.f, s1 = 0.f, s2 = 0.f, s3 = 0.f;
        for (int c = 0; c < C; ++c) {
            float4 a = f0v[(size_t)c * hw4 + idx];
            float4 b = f1v[(size_t)c * hw4 + idx];
            float e0 = a.x - b.x + EPS, e1 = a.y - b.y + EPS;
            float e2 = a.z - b.z + EPS, e3 = a.w - b.w + EPS;
            s0 = fmaf(e0, e0, s0); s1 = fmaf(e1, e1, s1);
            s2 = fmaf(e2, e2, s2); s3 = fmaf(e3, e3, s3);
        }
        int4 g = ((const int4*)gt)[idx];
        float d[4] = { sqrtf(s0), sqrtf(s1), sqrtf(s2), sqrtf(s3) };
        int gg[4] = { g.x, g.y, g.z, g.w };
        int posc = 0;
        #pragma unroll
        for (int k = 0; k < 4; ++k) {
            posc += (gg[k] == 0) ? 1 : 0;
            float dd = d[k];
            if (dd <= 1.0f) {
                int bin = (int)(dd * (float)NUM_BINS);
                if (bin > NUM_BINS - 1) bin = NUM_BINS - 1;
                atomicAdd(&sh[bin + ((gg[k] != 0) ? NUM_BINS : 0)], 1u);
            }
        }
        if (posc) atomicAdd(&sh[2 * NUM_BINS], (unsigned)posc);
    }
    __syncthreads();
    for (int i = threadIdx.x; i < WS_WORDS; i += blockDim.x) {
        unsigned v = sh[i];
        if (v) atomicAdd(&ws[i], v);
    }
}

__global__ void hml_final(const unsigned int* __restrict__ ws,
                          float* __restrict__ out, int hw)
{
    __shared__ float terms[NUM_BINS];
    int i = threadIdx.x;
    unsigned pos = ws[2 * NUM_BINS];
    float pos_size = (float)pos;
    float neg_size = (float)(hw - (int)pos);
    if (i < NUM_BINS) {
        float hp = (float)ws[i] / pos_size;
        unsigned cn = ws[NUM_BINS + i];
        float hn = (float)cn / neg_size;
        terms[i] = (cn > 0u) ? hn * (logf(hn) - hp) : 0.0f;
    }
    __syncthreads();
    if (i == 0) {
        float s = 0.f;
        for (int k = 0; k < NUM_BINS; ++k) s += terms[k];
        out[0] = 1.0f + s / (float)NUM_BINS;
    }
}

extern "C" void kernel_launch(void* const* d_in, const int* in_sizes, int n_in,
                              void* d_out, int out_size, void* d_ws, size_t ws_size,
                              hipStream_t stream) {
    const float* f0 = (const float*)d_in[0];
    const float* f1 = (const float*)d_in[1];
    const int*   gt = (const int*)d_in[2];
    float* out = (float*)d_out;
    unsigned int* ws = (unsigned int*)d_ws;

    const int hw = in_sizes[2];          // h*w (= 1024*1024)
    const int C  = in_sizes[0] / hw;     // channels (= 32)

    hml_init_ws<<<1, 256, 0, stream>>>(ws);

    if (C == 32 && (hw & 1023) == 0) {
        const int hw4 = hw >> 2;
        const int blocks = hw4 / 256;    // 1024 at 1024x1024
        hml_hist32<<<blocks, 256, 0, stream>>>(
            (const vfloat4*)f0, (const vfloat4*)f1, (const vint4*)gt, ws, hw4);
    } else {
        const int hw4 = hw >> 2;
        const int blocks = (hw4 + 255) / 256;
        hml_hist_generic<<<blocks, 256, 0, stream>>>(f0, f1, gt, ws, hw, C);
    }

    hml_final<<<1, 128, 0, stream>>>(ws, out, hw);
}

// Round 7
// 260.750 us; speedup vs baseline: 1.3663x; 1.0056x over previous
//
#include <hip/hip_runtime.h>
#include <math.h>

#define NUM_BINS 100
#define EPS 1e-6f

// ws layout (uint32): [0..99] pos-bin counts, [100..199] neg-bin counts, [200] pos pixel count
#define WS_WORDS (2 * NUM_BINS + 1)

// native vector types: __builtin_nontemporal_load requires these (not HIP_vector_type)
typedef float  vfloat4 __attribute__((ext_vector_type(4)));
typedef int    vint4   __attribute__((ext_vector_type(4)));

__global__ void hml_init_ws(unsigned int* __restrict__ ws) {
    int i = blockIdx.x * blockDim.x + threadIdx.x;
    if (i < WS_WORDS) ws[i] = 0u;
}

// C=32 specialized: 4 px/thread via float4, NT loads (R6 win: bypasses the
// per-CU L1 miss-tracking cap, 106 -> <78us). R7 single change: channel batch
// 4 -> 8 (16 NT loads in flight/thread) to probe whether L2-level miss
// parallelism is the next limiter. No launch_bounds cap (spill guard:
// WRITE_SIZE must stay ~KB-scale).
__global__ __launch_bounds__(256) void hml_hist32(
    const vfloat4* __restrict__ f0v, const vfloat4* __restrict__ f1v,
    const vint4* __restrict__ gt, unsigned int* __restrict__ ws, int hw4)
{
    __shared__ unsigned int sh[WS_WORDS];
    for (int i = threadIdx.x; i < WS_WORDS; i += 256) sh[i] = 0u;
    __syncthreads();

    const int idx = blockIdx.x * 256 + threadIdx.x;

    vint4 g = __builtin_nontemporal_load(&gt[idx]);
    float s0 = 0.f, s1 = 0.f, s2 = 0.f, s3 = 0.f;

    #pragma unroll
    for (int cg = 0; cg < 32; cg += 8) {
        vfloat4 a[8], b[8];
        #pragma unroll
        for (int j = 0; j < 8; ++j)
            a[j] = __builtin_nontemporal_load(&f0v[(size_t)(cg + j) * hw4 + idx]);
        #pragma unroll
        for (int j = 0; j < 8; ++j)
            b[j] = __builtin_nontemporal_load(&f1v[(size_t)(cg + j) * hw4 + idx]);
        #pragma unroll
        for (int j = 0; j < 8; ++j) {
            float e0 = a[j].x - b[j].x + EPS;
            float e1 = a[j].y - b[j].y + EPS;
            float e2 = a[j].z - b[j].z + EPS;
            float e3 = a[j].w - b[j].w + EPS;
            s0 = fmaf(e0, e0, s0);
            s1 = fmaf(e1, e1, s1);
            s2 = fmaf(e2, e2, s2);
            s3 = fmaf(e3, e3, s3);
        }
    }

    float d[4] = { sqrtf(s0), sqrtf(s1), sqrtf(s2), sqrtf(s3) };
    int gg[4] = { g.x, g.y, g.z, g.w };

    // pos-pixel count: shfl-reduce per wave, one LDS atomic per wave
    int posc = (gg[0] == 0) + (gg[1] == 0) + (gg[2] == 0) + (gg[3] == 0);
    for (int off = 32; off > 0; off >>= 1)
        posc += __shfl_down(posc, off, 64);
    if ((threadIdx.x & 63) == 0 && posc)
        atomicAdd(&sh[2 * NUM_BINS], (unsigned)posc);

    #pragma unroll
    for (int k = 0; k < 4; ++k) {
        float dd = d[k];
        // histc: values in [0,1] only (dd>=0 from sqrt); floor(d*100) clip 99
        if (dd <= 1.0f) {
            int bin = (int)(dd * (float)NUM_BINS);
            if (bin > NUM_BINS - 1) bin = NUM_BINS - 1;
            atomicAdd(&sh[bin + ((gg[k] != 0) ? NUM_BINS : 0)], 1u);
        }
    }

    __syncthreads();
    for (int i = threadIdx.x; i < WS_WORDS; i += 256) {
        unsigned v = sh[i];
        if (v) atomicAdd(&ws[i], v);
    }
}

// Generic fallback (any C, hw multiple of 4).
__global__ __launch_bounds__(256) void hml_hist_generic(
    const float* __restrict__ f0, const float* __restrict__ f1,
    const int* __restrict__ gt, unsigned int* __restrict__ ws,
    int hw, int C)
{
    __shared__ unsigned int sh[WS_WORDS];
    for (int i = threadIdx.x; i < WS_WORDS; i += blockDim.x) sh[i] = 0u;
    __syncthreads();

    const int hw4 = hw >> 2;
    const int idx = blockIdx.x * blockDim.x + threadIdx.x;

    if (idx < hw4) {
        const float4* __restrict__ f0v = (const float4*)f0;
        const float4* __restrict__ f1v = (const float4*)f1;
        float s0 = 0.f, s1 = 0.f, s2 = 0.f, s3 = 0.f;
        for (int c = 0; c < C; ++c) {
            float4 a = f0v[(size_t)c * hw4 + idx];
            float4 b = f1v[(size_t)c * hw4 + idx];
            float e0 = a.x - b.x + EPS, e1 = a.y - b.y + EPS;
            float e2 = a.z - b.z + EPS, e3 = a.w - b.w + EPS;
            s0 = fmaf(e0, e0, s0); s1 = fmaf(e1, e1, s1);
            s2 = fmaf(e2, e2, s2); s3 = fmaf(e3, e3, s3);
        }
        int4 g = ((const int4*)gt)[idx];
        float d[4] = { sqrtf(s0), sqrtf(s1), sqrtf(s2), sqrtf(s3) };
        int gg[4] = { g.x, g.y, g.z, g.w };
        int posc = 0;
        #pragma unroll
        for (int k = 0; k < 4; ++k) {
            posc += (gg[k] == 0) ? 1 : 0;
            float dd = d[k];
            if (dd <= 1.0f) {
                int bin = (int)(dd * (float)NUM_BINS);
                if (bin > NUM_BINS - 1) bin = NUM_BINS - 1;
                atomicAdd(&sh[bin + ((gg[k] != 0) ? NUM_BINS : 0)], 1u);
            }
        }
        if (posc) atomicAdd(&sh[2 * NUM_BINS], (unsigned)posc);
    }
    __syncthreads();
    for (int i = threadIdx.x; i < WS_WORDS; i += blockDim.x) {
        unsigned v = sh[i];
        if (v) atomicAdd(&ws[i], v);
    }
}

__global__ void hml_final(const unsigned int* __restrict__ ws,
                          float* __restrict__ out, int hw)
{
    __shared__ float terms[NUM_BINS];
    int i = threadIdx.x;
    unsigned pos = ws[2 * NUM_BINS];
    float pos_size = (float)pos;
    float neg_size = (float)(hw - (int)pos);
    if (i < NUM_BINS) {
        float hp = (float)ws[i] / pos_size;
        unsigned cn = ws[NUM_BINS + i];
        float hn = (float)cn / neg_size;
        terms[i] = (cn > 0u) ? hn * (logf(hn) - hp) : 0.0f;
    }
    __syncthreads();
    if (i == 0) {
        float s = 0.f;
        for (int k = 0; k < NUM_BINS; ++k) s += terms[k];
        out[0] = 1.0f + s / (float)NUM_BINS;
    }
}

extern "C" void kernel_launch(void* const* d_in, const int* in_sizes, int n_in,
                              void* d_out, int out_size, void* d_ws, size_t ws_size,
                              hipStream_t stream) {
    const float* f0 = (const float*)d_in[0];
    const float* f1 = (const float*)d_in[1];
    const int*   gt = (const int*)d_in[2];
    float* out = (float*)d_out;
    unsigned int* ws = (unsigned int*)d_ws;

    const int hw = in_sizes[2];          // h*w (= 1024*1024)
    const int C  = in_sizes[0] / hw;     // channels (= 32)

    hml_init_ws<<<1, 256, 0, stream>>>(ws);

    if (C == 32 && (hw & 1023) == 0) {
        const int hw4 = hw >> 2;
        const int blocks = hw4 / 256;    // 1024 at 1024x1024
        hml_hist32<<<blocks, 256, 0, stream>>>(
            (const vfloat4*)f0, (const vfloat4*)f1, (const vint4*)gt, ws, hw4);
    } else {
        const int hw4 = hw >> 2;
        const int blocks = (hw4 + 255) / 256;
        hml_hist_generic<<<blocks, 256, 0, stream>>>(f0, f1, gt, ws, hw, C);
    }

    hml_final<<<1, 128, 0, stream>>>(ws, out, hw);
}